// Round 2
// baseline (429.040 us; speedup 1.0000x reference)
//
#include <hip/hip_runtime.h>
#include <stdint.h>

#define VOCAB     128000
#define BINS      4096
#define BPR       8                 // blocks per row in the main pass
#define TPB       1024              // threads per block (main pass)
#define EPB       (TPB * 16)        // 16384 floats per block (4 x float4 / thread)
#define CAND_CAP  2048              // per-row candidate capacity (LDS + ws)
#define KEEP_CAP  128

#define BITS_SCHEME 2               // 2 = JAX partitionable threefry (verified round 1)

__device__ __forceinline__ uint32_t rotl32(uint32_t x, uint32_t r) {
    return (x << r) | (x >> (32u - r));
}

// monotone float -> uint transform (total order)
__device__ __forceinline__ uint32_t f2ord(float f) {
    uint32_t u = __float_as_uint(f);
    return (u & 0x80000000u) ? ~u : (u | 0x80000000u);
}

// Threefry-2x32, 20 rounds, key = (0, 42)  [jax.random.key(42)]
__device__ __forceinline__ void threefry_0_42(uint32_t x0, uint32_t x1,
                                              uint32_t& o0, uint32_t& o1) {
    const uint32_t k0 = 0u, k1 = 42u;
    const uint32_t k2 = 0x1BD11BDAu ^ k0 ^ k1;
#define TF_RND(R) { x0 += x1; x1 = rotl32(x1, (R)); x1 ^= x0; }
    x0 += k0; x1 += k1;
    TF_RND(13) TF_RND(15) TF_RND(26) TF_RND(6)
    x0 += k1; x1 += k2 + 1u;
    TF_RND(17) TF_RND(29) TF_RND(16) TF_RND(24)
    x0 += k2; x1 += k0 + 2u;
    TF_RND(13) TF_RND(15) TF_RND(26) TF_RND(6)
    x0 += k0; x1 += k1 + 3u;
    TF_RND(17) TF_RND(29) TF_RND(16) TF_RND(24)
    x0 += k1; x1 += k2 + 4u;
    TF_RND(13) TF_RND(15) TF_RND(26) TF_RND(6)
    x0 += k2; x1 += k0 + 5u;
#undef TF_RND
    o0 = x0; o1 = x1;
}

__device__ __forceinline__ float gumbel_at(uint64_t flat) {
    uint32_t bits, o0, o1;
    threefry_0_42((uint32_t)(flat >> 32), (uint32_t)flat, o0, o1);
    bits = o0 ^ o1;
    float f = __uint_as_float((bits >> 9) | 0x3F800000u) - 1.0f;
    float u = (f == 0.0f) ? 1.17549435e-38f : f;
    return -logf(-logf(u));
}

// ---------------------------------------------------------------------------
// Pass 1: per-(row,chunk) block. Reads its 16384-float chunk ONCE into regs,
// zero-fills its probs chunk, histograms scores, finds local top-K bin
// threshold, pushes all chunk elements >= threshold to the per-row candidate
// list in global ws. Union of local top-K supersets the global top-K.
// ---------------------------------------------------------------------------
extern "C" __global__ __launch_bounds__(TPB)
void hist_collect_kernel(const float* __restrict__ logits,
                         const float* __restrict__ temp_p,
                         const int*   __restrict__ topk_p,
                         float* __restrict__ out,
                         float* __restrict__ candV,
                         int*   __restrict__ candI,
                         int*   __restrict__ counters,
                         int batch, int cap) {
    const int row = blockIdx.x / BPR;
    const int sub = blockIdx.x % BPR;
    const int c0  = sub * EPB;
    const int c1  = min(c0 + EPB, VOCAB);
    const int n4  = (c1 - c0) >> 2;          // float4 count in this chunk
    const int tid = threadIdx.x;

    const float T = temp_p[0];
    const int   K = topk_p[0];

    __shared__ int hist[BINS];
    __shared__ int s_grp[256];
    __shared__ int s_tbin;

    for (int i = tid; i < BINS; i += TPB) hist[i] = 0;
    __syncthreads();

    const float4* rowp = (const float4*)(logits + (size_t)row * VOCAB) + (c0 >> 2);
    float4*       orow = (float4*)(out + batch + (size_t)row * VOCAB) + (c0 >> 2);
    const float4 z4 = make_float4(0.0f, 0.0f, 0.0f, 0.0f);

    float4 sv[4];
    #pragma unroll
    for (int k = 0; k < 4; ++k) {
        int i = tid + k * TPB;
        if (i < n4) {
            float4 v = rowp[i];
            float4 s;
            s.x = v.x / T; s.y = v.y / T; s.z = v.z / T; s.w = v.w / T;
            sv[k] = s;
            atomicAdd(&hist[f2ord(s.x) >> 20], 1);
            atomicAdd(&hist[f2ord(s.y) >> 20], 1);
            atomicAdd(&hist[f2ord(s.z) >> 20], 1);
            atomicAdd(&hist[f2ord(s.w) >> 20], 1);
            orow[i] = z4;                     // zero-fill probs in same pass
        }
    }
    __syncthreads();

    // local top-K bin threshold: group sums then serial top-down scan
    if (tid < 256) {
        int s = 0;
        #pragma unroll
        for (int b = 0; b < 16; ++b) s += hist[tid * 16 + b];
        s_grp[tid] = s;
    }
    __syncthreads();
    if (tid == 0) {
        int cum = 0, g = 255;
        for (; g > 0; --g) {
            if (cum + s_grp[g] >= K) break;
            cum += s_grp[g];
        }
        int tb = g * 16;
        for (int b = g * 16 + 15; ; --b) {
            cum += hist[b];
            if (cum >= K || b == g * 16) { tb = b; break; }
        }
        s_tbin = tb;
    }
    __syncthreads();
    const uint32_t tbin = (uint32_t)s_tbin;

    // push candidates from registers (no re-read of HBM)
    int* ctr = &counters[row];
    float* cVrow = candV + (size_t)row * cap;
    int*   cIrow = candI + (size_t)row * cap;
    #pragma unroll
    for (int k = 0; k < 4; ++k) {
        int i = tid + k * TPB;
        if (i < n4) {
            float ss[4] = { sv[k].x, sv[k].y, sv[k].z, sv[k].w };
            int e = c0 + i * 4;
            #pragma unroll
            for (int c = 0; c < 4; ++c) {
                if ((f2ord(ss[c]) >> 20) >= tbin) {
                    int p = atomicAdd(ctr, 1);
                    if (p < cap) { cVrow[p] = ss[c]; cIrow[p] = e + c; }
                }
            }
        }
    }
}

// ---------------------------------------------------------------------------
// Pass 2: per-row finalize. Rank-sort candidates, then the (round-1 verified)
// serial top-k/top-p/softmax + Gumbel-argmax, scatter probs + token.
// ---------------------------------------------------------------------------
extern "C" __global__ __launch_bounds__(512)
void finalize_kernel(const float* __restrict__ topp_p,
                     const int*   __restrict__ topk_p,
                     const float* __restrict__ candV,
                     const int*   __restrict__ candI,
                     const int*   __restrict__ counters,
                     float* __restrict__ out,
                     int batch, int cap) {
    const int row = blockIdx.x;
    const int tid = threadIdx.x;
    const int nthr = blockDim.x;

    const float thresh = 1.0f - topp_p[0];
    const int   K      = topk_p[0];

    __shared__ float cV[CAND_CAP];
    __shared__ int   cI[CAND_CAP];
    __shared__ float sortedV[CAND_CAP];
    __shared__ int   sortedI[CAND_CAP];
    __shared__ float keptP[KEEP_CAP];
    __shared__ int   keptI[KEEP_CAP];
    __shared__ float s_gs[KEEP_CAP];
    __shared__ int   s_M;
    __shared__ int   s_token;

    const int n = min(counters[row], cap);
    const float* cVrow = candV + (size_t)row * cap;
    const int*   cIrow = candI + (size_t)row * cap;
    for (int i = tid; i < n; i += nthr) { cV[i] = cVrow[i]; cI[i] = cIrow[i]; }
    __syncthreads();

    // rank sort descending (unique total order via index tiebreak)
    for (int j = tid; j < n; j += nthr) {
        float vj = cV[j]; int ij = cI[j];
        int r = 0;
        for (int l = 0; l < n; ++l) {
            float vl = cV[l];
            r += (vl > vj) || (vl == vj && cI[l] < ij);
        }
        sortedV[r] = vj; sortedI[r] = ij;
    }
    __syncthreads();

    // serial small math: top-k kth, top-p cut, final softmax (round-1 verified)
    if (tid == 0) {
        int Keff = min(K, n);
        float kth = sortedV[Keff - 1];
        int Kp = Keff;
        while (Kp < n && sortedV[Kp] == kth) ++Kp;

        float m = sortedV[0];
        float Z = 0.0f;
        for (int j = Kp - 1; j >= 0; --j) Z += expf(sortedV[j] - m);
        float cum = 0.0f; int jcut = 0;
        for (int j = Kp - 1; j >= 0; --j) {
            cum += expf(sortedV[j] - m) / Z;
            if (cum > thresh) { jcut = j; break; }
        }
        int M = jcut + 1;
        if (M > KEEP_CAP) M = KEEP_CAP;
        float Z2 = 0.0f;
        for (int j = 0; j < M; ++j) Z2 += expf(sortedV[j] - m);
        for (int j = 0; j < M; ++j) {
            keptP[j] = expf(sortedV[j] - m) / Z2;
            keptI[j] = sortedI[j];
        }
        s_M = M;
    }
    __syncthreads();
    const int M = s_M;

    if (tid < M) {
        uint64_t flat = (uint64_t)row * VOCAB + (uint32_t)keptI[tid];
        s_gs[tid] = sortedV[tid] + gumbel_at(flat);
    }
    __syncthreads();
    if (tid == 0) {
        float bs = -__builtin_inff(); int bi = 0x7fffffff;
        for (int j = 0; j < M; ++j) {
            float s = s_gs[j]; int c = keptI[j];
            if (s > bs || (s == bs && c < bi)) { bs = s; bi = c; }
        }
        s_token = bi;
    }
    __syncthreads();

    // probs row already zeroed by pass 1 — just scatter kept probs + token
    for (int j = tid; j < M; j += nthr) {
        out[batch + (size_t)row * VOCAB + keptI[j]] = keptP[j];
    }
    if (tid == 0) out[row] = (float)s_token;
}

extern "C" void kernel_launch(void* const* d_in, const int* in_sizes, int n_in,
                              void* d_out, int out_size, void* d_ws, size_t ws_size,
                              hipStream_t stream) {
    (void)n_in; (void)out_size;
    const float* logits = (const float*)d_in[0];
    const float* temp   = (const float*)d_in[1];
    const float* topp   = (const float*)d_in[2];
    const int*   topk   = (const int*)d_in[3];
    float* out = (float*)d_out;

    const int batch = in_sizes[0] / VOCAB;

    // ws layout: [counters: batch ints][candV: batch*cap floats][candI: batch*cap ints]
    size_t ctr_bytes = ((size_t)batch * sizeof(int) + 255) & ~(size_t)255;
    int cap = CAND_CAP;
    if (ws_size > ctr_bytes) {
        size_t per_row = (ws_size - ctr_bytes) / ((size_t)batch * 8);
        if (per_row < (size_t)cap) cap = (int)per_row;
    }
    int*   counters = (int*)d_ws;
    float* candV    = (float*)((char*)d_ws + ctr_bytes);
    int*   candI    = (int*)(candV + (size_t)batch * cap);

    hipMemsetAsync(counters, 0, (size_t)batch * sizeof(int), stream);

    hist_collect_kernel<<<batch * BPR, TPB, 0, stream>>>(
        logits, temp, topk, out, candV, candI, counters, batch, cap);

    finalize_kernel<<<batch, 512, 0, stream>>>(
        topp, topk, candV, candI, counters, out, batch, cap);
}

// Round 3
// 166.945 us; speedup vs baseline: 2.5700x; 2.5700x over previous
//
#include <hip/hip_runtime.h>
#include <stdint.h>

#define VOCAB     128000
#define BINS      4096
#define BPR       4                 // blocks per row in the main pass
#define TPB       1024              // threads per block (main pass)
#define CHUNK     (VOCAB / BPR)     // 32000 floats per block
#define N4C       (CHUNK / 4)       // 8000 float4 per block
#define CAND_CAP  1024              // per-row candidate capacity
#define KEEP_CAP  128

__device__ __forceinline__ uint32_t rotl32(uint32_t x, uint32_t r) {
    return (x << r) | (x >> (32u - r));
}

// monotone float -> uint transform (total order)
__device__ __forceinline__ uint32_t f2ord(float f) {
    uint32_t u = __float_as_uint(f);
    return (u & 0x80000000u) ? ~u : (u | 0x80000000u);
}

// Threefry-2x32, 20 rounds, key = (0, 42)  [jax.random.key(42)] — verified round 1
__device__ __forceinline__ void threefry_0_42(uint32_t x0, uint32_t x1,
                                              uint32_t& o0, uint32_t& o1) {
    const uint32_t k0 = 0u, k1 = 42u;
    const uint32_t k2 = 0x1BD11BDAu ^ k0 ^ k1;
#define TF_RND(R) { x0 += x1; x1 = rotl32(x1, (R)); x1 ^= x0; }
    x0 += k0; x1 += k1;
    TF_RND(13) TF_RND(15) TF_RND(26) TF_RND(6)
    x0 += k1; x1 += k2 + 1u;
    TF_RND(17) TF_RND(29) TF_RND(16) TF_RND(24)
    x0 += k2; x1 += k0 + 2u;
    TF_RND(13) TF_RND(15) TF_RND(26) TF_RND(6)
    x0 += k0; x1 += k1 + 3u;
    TF_RND(17) TF_RND(29) TF_RND(16) TF_RND(24)
    x0 += k1; x1 += k2 + 4u;
    TF_RND(13) TF_RND(15) TF_RND(26) TF_RND(6)
    x0 += k2; x1 += k0 + 5u;
#undef TF_RND
    o0 = x0; o1 = x1;
}

__device__ __forceinline__ float gumbel_at(uint64_t flat) {
    uint32_t o0, o1;
    threefry_0_42((uint32_t)(flat >> 32), (uint32_t)flat, o0, o1);
    uint32_t bits = o0 ^ o1;
    float f = __uint_as_float((bits >> 9) | 0x3F800000u) - 1.0f;
    float u = (f == 0.0f) ? 1.17549435e-38f : f;
    return -logf(-logf(u));
}

// ---------------------------------------------------------------------------
// Pass 1: per-(row,chunk) block. Pass A: read chunk, zero probs, histogram.
// Pass B: local top-K bin threshold. Pass C: RE-READ chunk from L2 (no
// register carry — round 2's register version spilled to scratch and
// latency-stalled the kernel), push candidates >= threshold.
// Union of per-chunk top-K supersets the global top-K.
// ---------------------------------------------------------------------------
extern "C" __global__ __launch_bounds__(TPB)
void hist_collect_kernel(const float* __restrict__ logits,
                         const float* __restrict__ temp_p,
                         const int*   __restrict__ topk_p,
                         float* __restrict__ out,
                         float* __restrict__ candV,
                         int*   __restrict__ candI,
                         int*   __restrict__ counters,
                         int batch, int cap) {
    const int row = blockIdx.x / BPR;
    const int sub = blockIdx.x % BPR;
    const int c0  = sub * CHUNK;
    const int tid = threadIdx.x;

    const float T = temp_p[0];
    const int   K = topk_p[0];

    __shared__ int hist[BINS];
    __shared__ int s_grp[256];
    __shared__ int s_tbin;

    for (int i = tid; i < BINS; i += TPB) hist[i] = 0;
    __syncthreads();

    const float4* rowp = (const float4*)(logits + (size_t)row * VOCAB) + (c0 >> 2);
    float4*       orow = (float4*)(out + batch + (size_t)row * VOCAB) + (c0 >> 2);
    const float4 z4 = make_float4(0.0f, 0.0f, 0.0f, 0.0f);

    // pass A: histogram + zero-fill probs
    for (int i = tid; i < N4C; i += TPB) {
        float4 v = rowp[i];
        atomicAdd(&hist[f2ord(v.x / T) >> 20], 1);
        atomicAdd(&hist[f2ord(v.y / T) >> 20], 1);
        atomicAdd(&hist[f2ord(v.z / T) >> 20], 1);
        atomicAdd(&hist[f2ord(v.w / T) >> 20], 1);
        orow[i] = z4;
    }
    __syncthreads();

    // pass B: local top-K bin threshold (group sums + serial top-down scan)
    if (tid < 256) {
        int s = 0;
        #pragma unroll
        for (int b = 0; b < 16; ++b) s += hist[tid * 16 + b];
        s_grp[tid] = s;
    }
    __syncthreads();
    if (tid == 0) {
        int cum = 0, g = 255;
        for (; g > 0; --g) {
            if (cum + s_grp[g] >= K) break;
            cum += s_grp[g];
        }
        int tb = g * 16;
        for (int b = g * 16 + 15; ; --b) {
            cum += hist[b];
            if (cum >= K || b == g * 16) { tb = b; break; }
        }
        s_tbin = tb;
    }
    __syncthreads();
    const uint32_t tbin = (uint32_t)s_tbin;

    // pass C: re-read chunk (L2/L3-hot), push candidates
    int* ctr = &counters[row];
    float* cVrow = candV + (size_t)row * cap;
    int*   cIrow = candI + (size_t)row * cap;
    for (int i = tid; i < N4C; i += TPB) {
        float4 v = rowp[i];
        float s[4] = { v.x / T, v.y / T, v.z / T, v.w / T };
        int e = c0 + i * 4;
        #pragma unroll
        for (int c = 0; c < 4; ++c) {
            if ((f2ord(s[c]) >> 20) >= tbin) {
                int p = atomicAdd(ctr, 1);
                if (p < cap) { cVrow[p] = s[c]; cIrow[p] = e + c; }
            }
        }
    }
}

// ---------------------------------------------------------------------------
// Pass 2: per-row finalize. Rank-sort candidates, then the (verified) serial
// top-k/top-p/softmax + Gumbel-argmax, scatter probs + token.
// ---------------------------------------------------------------------------
extern "C" __global__ __launch_bounds__(1024)
void finalize_kernel(const float* __restrict__ topp_p,
                     const int*   __restrict__ topk_p,
                     const float* __restrict__ candV,
                     const int*   __restrict__ candI,
                     const int*   __restrict__ counters,
                     float* __restrict__ out,
                     int batch, int cap) {
    const int row = blockIdx.x;
    const int tid = threadIdx.x;
    const int nthr = blockDim.x;

    const float thresh = 1.0f - topp_p[0];
    const int   K      = topk_p[0];

    __shared__ float cV[CAND_CAP];
    __shared__ int   cI[CAND_CAP];
    __shared__ float sortedV[CAND_CAP];
    __shared__ int   sortedI[CAND_CAP];
    __shared__ float keptP[KEEP_CAP];
    __shared__ int   keptI[KEEP_CAP];
    __shared__ float s_gs[KEEP_CAP];
    __shared__ int   s_M;
    __shared__ int   s_token;

    const int n = min(counters[row], cap);
    const float* cVrow = candV + (size_t)row * cap;
    const int*   cIrow = candI + (size_t)row * cap;
    for (int i = tid; i < n; i += nthr) { cV[i] = cVrow[i]; cI[i] = cIrow[i]; }
    __syncthreads();

    // rank sort descending (unique total order via index tiebreak)
    for (int j = tid; j < n; j += nthr) {
        float vj = cV[j]; int ij = cI[j];
        int r = 0;
        for (int l = 0; l < n; ++l) {
            float vl = cV[l];
            r += (vl > vj) || (vl == vj && cI[l] < ij);
        }
        sortedV[r] = vj; sortedI[r] = ij;
    }
    __syncthreads();

    // serial small math: top-k kth, top-p cut, final softmax (verified)
    if (tid == 0) {
        int Keff = min(K, n);
        float kth = sortedV[Keff - 1];
        int Kp = Keff;
        while (Kp < n && sortedV[Kp] == kth) ++Kp;

        float m = sortedV[0];
        float Z = 0.0f;
        for (int j = Kp - 1; j >= 0; --j) Z += expf(sortedV[j] - m);
        float cum = 0.0f; int jcut = 0;
        for (int j = Kp - 1; j >= 0; --j) {
            cum += expf(sortedV[j] - m) / Z;
            if (cum > thresh) { jcut = j; break; }
        }
        int M = jcut + 1;
        if (M > KEEP_CAP) M = KEEP_CAP;
        float Z2 = 0.0f;
        for (int j = 0; j < M; ++j) Z2 += expf(sortedV[j] - m);
        for (int j = 0; j < M; ++j) {
            keptP[j] = expf(sortedV[j] - m) / Z2;
            keptI[j] = sortedI[j];
        }
        s_M = M;
    }
    __syncthreads();
    const int M = s_M;

    if (tid < M) {
        uint64_t flat = (uint64_t)row * VOCAB + (uint32_t)keptI[tid];
        s_gs[tid] = sortedV[tid] + gumbel_at(flat);
    }
    __syncthreads();
    if (tid == 0) {
        float bs = -__builtin_inff(); int bi = 0x7fffffff;
        for (int j = 0; j < M; ++j) {
            float s = s_gs[j]; int c = keptI[j];
            if (s > bs || (s == bs && c < bi)) { bs = s; bi = c; }
        }
        s_token = bi;
    }
    __syncthreads();

    // probs row already zeroed by pass 1 — scatter kept probs + token
    for (int j = tid; j < M; j += nthr) {
        out[batch + (size_t)row * VOCAB + keptI[j]] = keptP[j];
    }
    if (tid == 0) out[row] = (float)s_token;
}

extern "C" void kernel_launch(void* const* d_in, const int* in_sizes, int n_in,
                              void* d_out, int out_size, void* d_ws, size_t ws_size,
                              hipStream_t stream) {
    (void)n_in; (void)out_size;
    const float* logits = (const float*)d_in[0];
    const float* temp   = (const float*)d_in[1];
    const float* topp   = (const float*)d_in[2];
    const int*   topk   = (const int*)d_in[3];
    float* out = (float*)d_out;

    const int batch = in_sizes[0] / VOCAB;

    // ws layout: [counters: batch ints][candV: batch*cap floats][candI: batch*cap ints]
    size_t ctr_bytes = ((size_t)batch * sizeof(int) + 255) & ~(size_t)255;
    int cap = CAND_CAP;
    if (ws_size > ctr_bytes) {
        size_t per_row = (ws_size - ctr_bytes) / ((size_t)batch * 8);
        if (per_row < (size_t)cap) cap = (int)per_row;
    }
    int*   counters = (int*)d_ws;
    float* candV    = (float*)((char*)d_ws + ctr_bytes);
    int*   candI    = (int*)(candV + (size_t)batch * cap);

    hipMemsetAsync(counters, 0, (size_t)batch * sizeof(int), stream);

    hist_collect_kernel<<<batch * BPR, TPB, 0, stream>>>(
        logits, temp, topk, out, candV, candI, counters, batch, cap);

    finalize_kernel<<<batch, 1024, 0, stream>>>(
        topp, topk, candV, candI, counters, out, batch, cap);
}